// Round 4
// baseline (157.720 us; speedup 1.0000x reference)
//
#include <hip/hip_runtime.h>
#include <math.h>

#define NQ   512
#define NKV  1280
#define CDIM 128

// workspace layout (float offsets)
#define OFF_WDSUM 0        // 3
#define OFF_SUMS  16       // 1024: [br][512] row sums (zeroed by prep)
#define OFF_QSA   1056     // 65536 [n=512][c=128]
#define OFF_QDA   66592    // 65536
#define OFF_KSAT  132128   // 163840 [c=128][k=1280] transposed (coalesced score)
#define OFF_VSA   295968   // 163840 [k=1280][c=128] row-major (coalesced AV)
#define OFF_KDAT  459808   // 163840
#define OFF_VDA   623648   // 163840
#define OFF_OUT   787488   // 131072: [br][512][128] unnormalized AV (zeroed)
// total 918560 floats = 3.67 MB

// ---------------------------------------------------------------- prep
// bx<320: kv proj (4 keys); bx in [320,448): q proj (4 rows);
// bx==448: wdsum + zero sums; bx in [449,577): zero OUT.
__global__ __launch_bounds__(256) void prep_kernel(
    const float* __restrict__ erp, const float* __restrict__ ico,
    const float* __restrict__ wq_sa, const float* __restrict__ wq_da,
    const float* __restrict__ wkv_sa, const float* __restrict__ wkv_da,
    const float* __restrict__ wdelta, float* __restrict__ ws)
{
  int bx = blockIdx.x, t = threadIdx.x;
  if (bx < 320) {
    __shared__ float x4[4 * CDIM];          // [j*4 + ky]
    int k0 = bx * 4;
    for (int i = t; i < 512; i += 256) {
      int ky = i >> 7, j = i & 127;
      x4[j * 4 + ky] = ico[(k0 + ky) * CDIM + j];
    }
    __syncthreads();
    const float4* wsa4 = (const float4*)(wkv_sa + t * CDIM);
    const float4* wda4 = (const float4*)(wkv_da + t * CDIM);
    float as0=0,as1=0,as2=0,as3=0, ad0=0,ad1=0,ad2=0,ad3=0;
    #pragma unroll 4
    for (int j4 = 0; j4 < 32; ++j4) {
      float4 wsv = wsa4[j4];
      float4 wdv = wda4[j4];
      float4 x0 = *(const float4*)&x4[(j4 * 4 + 0) * 4];
      float4 x1 = *(const float4*)&x4[(j4 * 4 + 1) * 4];
      float4 x2 = *(const float4*)&x4[(j4 * 4 + 2) * 4];
      float4 x3 = *(const float4*)&x4[(j4 * 4 + 3) * 4];
      as0 = fmaf(wsv.x, x0.x, as0); as1 = fmaf(wsv.x, x0.y, as1);
      as2 = fmaf(wsv.x, x0.z, as2); as3 = fmaf(wsv.x, x0.w, as3);
      ad0 = fmaf(wdv.x, x0.x, ad0); ad1 = fmaf(wdv.x, x0.y, ad1);
      ad2 = fmaf(wdv.x, x0.z, ad2); ad3 = fmaf(wdv.x, x0.w, ad3);
      as0 = fmaf(wsv.y, x1.x, as0); as1 = fmaf(wsv.y, x1.y, as1);
      as2 = fmaf(wsv.y, x1.z, as2); as3 = fmaf(wsv.y, x1.w, as3);
      ad0 = fmaf(wdv.y, x1.x, ad0); ad1 = fmaf(wdv.y, x1.y, ad1);
      ad2 = fmaf(wdv.y, x1.z, ad2); ad3 = fmaf(wdv.y, x1.w, ad3);
      as0 = fmaf(wsv.z, x2.x, as0); as1 = fmaf(wsv.z, x2.y, as1);
      as2 = fmaf(wsv.z, x2.z, as2); as3 = fmaf(wsv.z, x2.w, as3);
      ad0 = fmaf(wdv.z, x2.x, ad0); ad1 = fmaf(wdv.z, x2.y, ad1);
      ad2 = fmaf(wdv.z, x2.z, ad2); ad3 = fmaf(wdv.z, x2.w, ad3);
      as0 = fmaf(wsv.w, x3.x, as0); as1 = fmaf(wsv.w, x3.y, as1);
      as2 = fmaf(wsv.w, x3.z, as2); as3 = fmaf(wsv.w, x3.w, as3);
      ad0 = fmaf(wdv.w, x3.x, ad0); ad1 = fmaf(wdv.w, x3.y, ad1);
      ad2 = fmaf(wdv.w, x3.z, ad2); ad3 = fmaf(wdv.w, x3.w, ad3);
    }
    if (t < 128) {   // k features -> transposed [c][k], float4 along k
      *(float4*)(ws + OFF_KSAT + t * NKV + k0) = make_float4(as0, as1, as2, as3);
      *(float4*)(ws + OFF_KDAT + t * NKV + k0) = make_float4(ad0, ad1, ad2, ad3);
    } else {         // v features -> [k][c] row-major (coalesced scalar stores)
      int c = t - 128;
      ws[OFF_VSA + (k0 + 0) * CDIM + c] = as0;
      ws[OFF_VSA + (k0 + 1) * CDIM + c] = as1;
      ws[OFF_VSA + (k0 + 2) * CDIM + c] = as2;
      ws[OFF_VSA + (k0 + 3) * CDIM + c] = as3;
      ws[OFF_VDA + (k0 + 0) * CDIM + c] = ad0;
      ws[OFF_VDA + (k0 + 1) * CDIM + c] = ad1;
      ws[OFF_VDA + (k0 + 2) * CDIM + c] = ad2;
      ws[OFF_VDA + (k0 + 3) * CDIM + c] = ad3;
    }
  } else if (bx < 448) {
    // q projection, 4 rows; t<128 -> q_sa out c=t, t>=128 -> q_da out c=t-128
    __shared__ float q4[4 * CDIM];          // [j*4 + r]
    int n0 = (bx - 320) * 4;
    for (int i = t; i < 512; i += 256)
      q4[i] = erp[(i >> 2) * NQ + n0 + (i & 3)];
    __syncthreads();
    const float* w = (t < 128) ? wq_sa : wq_da;
    int c = t & 127;
    const float4* w4 = (const float4*)(w + c * CDIM);
    float a0 = 0.f, a1 = 0.f, a2 = 0.f, a3 = 0.f;
    #pragma unroll 8
    for (int j4 = 0; j4 < 32; ++j4) {
      float4 wv = w4[j4];
      float4 q0 = *(const float4*)&q4[(j4 * 4 + 0) * 4];
      float4 q1 = *(const float4*)&q4[(j4 * 4 + 1) * 4];
      float4 q2 = *(const float4*)&q4[(j4 * 4 + 2) * 4];
      float4 q3 = *(const float4*)&q4[(j4 * 4 + 3) * 4];
      a0 = fmaf(wv.x, q0.x, a0); a1 = fmaf(wv.x, q0.y, a1);
      a2 = fmaf(wv.x, q0.z, a2); a3 = fmaf(wv.x, q0.w, a3);
      a0 = fmaf(wv.y, q1.x, a0); a1 = fmaf(wv.y, q1.y, a1);
      a2 = fmaf(wv.y, q1.z, a2); a3 = fmaf(wv.y, q1.w, a3);
      a0 = fmaf(wv.z, q2.x, a0); a1 = fmaf(wv.z, q2.y, a1);
      a2 = fmaf(wv.z, q2.z, a2); a3 = fmaf(wv.z, q2.w, a3);
      a0 = fmaf(wv.w, q3.x, a0); a1 = fmaf(wv.w, q3.y, a1);
      a2 = fmaf(wv.w, q3.z, a2); a3 = fmaf(wv.w, q3.w, a3);
    }
    float* o = ws + ((t < 128) ? OFF_QSA : OFF_QDA);
    o[(n0 + 0) * CDIM + c] = a0;
    o[(n0 + 1) * CDIM + c] = a1;
    o[(n0 + 2) * CDIM + c] = a2;
    o[(n0 + 3) * CDIM + c] = a3;
  } else if (bx == 448) {
    *(float4*)(ws + OFF_SUMS + t * 4) = make_float4(0.f, 0.f, 0.f, 0.f);
    if (t < 3) {   // Wdelta.sum(0)
      float s = 0.f;
      for (int i = 0; i < 128; ++i) s += wdelta[i * 3 + t];
      ws[OFF_WDSUM + t] = s;
    }
  } else {
    int base = OFF_OUT + (bx - 449) * 1024 + t * 4;
    *(float4*)(ws + base) = make_float4(0.f, 0.f, 0.f, 0.f);
  }
}

// ---------------------------------------------------------------- attn
// 1280 blocks, br = b&1 (da odd / sa even, interleaved for CU mix).
// Each block: 8 q-rows (g = (b>>1)/10), 128-k slice (z = (b>>1)%10).
// Score: thread t -> row h=t>>5, key-quad qd=t&31 (4 consecutive keys).
// K^T float4 loads (lane-contiguous 512B/wave-instr), 4 exp/FMA per load,
// full 128-j logit in registers -> 4x compute per load vs scalar version.
// Row sums: each 32-lane half-wave owns one full row -> shuffle reduce ->
// one atomicAdd. AV: thread (c=t&127, half=t>>7) covers 64-k half, 8 rows;
// se float4 broadcasts + lane-contiguous V scalars; 8 atomicAdds.
__global__ __launch_bounds__(256) void attn_kernel(
    const float* __restrict__ coord, float* __restrict__ ws)
{
  __shared__ __align__(16) float qjf[128][8];  // [j][r] 4KB
  __shared__ __align__(16) float se[8][128];   // exp(logit) 4KB
  __shared__ float qcr[8][3];
  __shared__ float wdl[3];
  int b = blockIdx.x, t = threadIdx.x;
  int br = b & 1;
  int bb = b >> 1;
  int g = bb / 10, z = bb - g * 10;
  int n0 = g * 8, k0 = z * 128;

  const float* qsrc = ws + (br ? OFF_QDA : OFF_QSA);
  for (int i = t; i < 1024; i += 256) {
    int j = i & 127, r = i >> 7;
    qjf[j][r] = qsrc[(n0 + r) * CDIM + j];
  }
  if (br) {
    if (t < 8) {
      int n = n0 + t;
      float x = (float)(n & 31), y = (float)(n >> 5);
      float u  = (x - 16.5f) * 0.19634954084936207f;  // pi/16
      float vv = (y -  8.5f) * 0.19634954084936207f;
      float cv = cosf(vv);
      qcr[t][0] = cv * sinf(u);
      qcr[t][1] = sinf(vv);
      qcr[t][2] = cv * cosf(u);
    }
    if (t >= 64 && t < 67) wdl[t - 64] = ws[OFF_WDSUM + (t - 64)];
  }
  __syncthreads();

  int qd = t & 31, h = t >> 5;      // key quad, row
  int kq = k0 + qd * 4;
  float acc0 = 0.f, acc1 = 0.f, acc2 = 0.f, acc3 = 0.f;
  float e0, e1, e2, e3;

  if (br) {
    // coords for this thread's 4 keys (12 floats, 16B-aligned)
    const float4* cp = (const float4*)(coord + kq * 3);
    float4 ca = cp[0], cb = cp[1], cc = cp[2];
    const float4* kt = (const float4*)(ws + OFF_KDAT + kq);
    #pragma unroll 4
    for (int j = 0; j < 128; ++j) {
      float4 kv = kt[j * (NKV / 4)];
      float qv = qjf[j][h];
      acc0 += __expf(-fabsf(qv - kv.x));
      acc1 += __expf(-fabsf(qv - kv.y));
      acc2 += __expf(-fabsf(qv - kv.z));
      acc3 += __expf(-fabsf(qv - kv.w));
    }
    float w0 = wdl[0], w1 = wdl[1], w2 = wdl[2];
    float q0 = qcr[h][0], q1 = qcr[h][1], q2 = qcr[h][2];
    float p0 = w0 * __expf(-fabsf(q0 - ca.x))
             + w1 * __expf(-fabsf(q1 - ca.y))
             + w2 * __expf(-fabsf(q2 - ca.z));
    float p1 = w0 * __expf(-fabsf(q0 - ca.w))
             + w1 * __expf(-fabsf(q1 - cb.x))
             + w2 * __expf(-fabsf(q2 - cb.y));
    float p2 = w0 * __expf(-fabsf(q0 - cb.z))
             + w1 * __expf(-fabsf(q1 - cb.w))
             + w2 * __expf(-fabsf(q2 - cc.x));
    float p3 = w0 * __expf(-fabsf(q0 - cc.y))
             + w1 * __expf(-fabsf(q1 - cc.z))
             + w2 * __expf(-fabsf(q2 - cc.w));
    const float i128 = 0.0078125f;        // 1/C
    e0 = __expf((acc0 + p0) * i128);
    e1 = __expf((acc1 + p1) * i128);
    e2 = __expf((acc2 + p2) * i128);
    e3 = __expf((acc3 + p3) * i128);
  } else {
    const float4* kt = (const float4*)(ws + OFF_KSAT + kq);
    #pragma unroll 8
    for (int j = 0; j < 128; ++j) {
      float4 kv = kt[j * (NKV / 4)];
      float qv = qjf[j][h];
      acc0 = fmaf(qv, kv.x, acc0);
      acc1 = fmaf(qv, kv.y, acc1);
      acc2 = fmaf(qv, kv.z, acc2);
      acc3 = fmaf(qv, kv.w, acc3);
    }
    const float scl = 0.088388347648318447f;  // 128^-0.5
    e0 = __expf(acc0 * scl);
    e1 = __expf(acc1 * scl);
    e2 = __expf(acc2 * scl);
    e3 = __expf(acc3 * scl);
  }
  *(float4*)&se[h][qd * 4] = make_float4(e0, e1, e2, e3);

  // row sum: each 32-lane group owns one full row (32 quads = 128 keys)
  float s = (e0 + e1) + (e2 + e3);
  #pragma unroll
  for (int o = 16; o > 0; o >>= 1) s += __shfl_down(s, o, 32);
  if ((t & 31) == 0)
    atomicAdd(ws + OFF_SUMS + br * 512 + n0 + h, s);
  __syncthreads();   // covers se[]

  // AV: thread (c=t&127, half=t>>7) handles 64-k half, all 8 rows.
  int c = t & 127, half = t >> 7;
  int kb = half * 64;
  const float* vp = ws + (br ? OFF_VDA : OFF_VSA) + (k0 + kb) * CDIM + c;
  float a0 = 0.f, a1 = 0.f, a2 = 0.f, a3 = 0.f;
  float a4 = 0.f, a5 = 0.f, a6 = 0.f, a7 = 0.f;
  #pragma unroll 2
  for (int ko = 0; ko < 64; ko += 4) {
    int kk = kb + ko;
    float4 p0 = *(const float4*)&se[0][kk];
    float4 p1 = *(const float4*)&se[1][kk];
    float4 p2 = *(const float4*)&se[2][kk];
    float4 p3 = *(const float4*)&se[3][kk];
    float4 p4 = *(const float4*)&se[4][kk];
    float4 p5 = *(const float4*)&se[5][kk];
    float4 p6 = *(const float4*)&se[6][kk];
    float4 p7 = *(const float4*)&se[7][kk];
    float v0 = vp[(ko + 0) * CDIM];
    float v1 = vp[(ko + 1) * CDIM];
    float v2 = vp[(ko + 2) * CDIM];
    float v3 = vp[(ko + 3) * CDIM];
    a0 = fmaf(p0.x, v0, a0); a0 = fmaf(p0.y, v1, a0);
    a0 = fmaf(p0.z, v2, a0); a0 = fmaf(p0.w, v3, a0);
    a1 = fmaf(p1.x, v0, a1); a1 = fmaf(p1.y, v1, a1);
    a1 = fmaf(p1.z, v2, a1); a1 = fmaf(p1.w, v3, a1);
    a2 = fmaf(p2.x, v0, a2); a2 = fmaf(p2.y, v1, a2);
    a2 = fmaf(p2.z, v2, a2); a2 = fmaf(p2.w, v3, a2);
    a3 = fmaf(p3.x, v0, a3); a3 = fmaf(p3.y, v1, a3);
    a3 = fmaf(p3.z, v2, a3); a3 = fmaf(p3.w, v3, a3);
    a4 = fmaf(p4.x, v0, a4); a4 = fmaf(p4.y, v1, a4);
    a4 = fmaf(p4.z, v2, a4); a4 = fmaf(p4.w, v3, a4);
    a5 = fmaf(p5.x, v0, a5); a5 = fmaf(p5.y, v1, a5);
    a5 = fmaf(p5.z, v2, a5); a5 = fmaf(p5.w, v3, a5);
    a6 = fmaf(p6.x, v0, a6); a6 = fmaf(p6.y, v1, a6);
    a6 = fmaf(p6.z, v2, a6); a6 = fmaf(p6.w, v3, a6);
    a7 = fmaf(p7.x, v0, a7); a7 = fmaf(p7.y, v1, a7);
    a7 = fmaf(p7.z, v2, a7); a7 = fmaf(p7.w, v3, a7);
  }
  float* op = ws + OFF_OUT + br * (NQ * CDIM) + c;
  atomicAdd(op + (n0 + 0) * CDIM, a0);
  atomicAdd(op + (n0 + 1) * CDIM, a1);
  atomicAdd(op + (n0 + 2) * CDIM, a2);
  atomicAdd(op + (n0 + 3) * CDIM, a3);
  atomicAdd(op + (n0 + 4) * CDIM, a4);
  atomicAdd(op + (n0 + 5) * CDIM, a5);
  atomicAdd(op + (n0 + 6) * CDIM, a6);
  atomicAdd(op + (n0 + 7) * CDIM, a7);
}

// ---------------------------------------------------------------- finalize
// one block (256 thr) per 2 query rows: normalize (divide by sums) with the
// reference's transpose-reshape on sa, project both, gate, fuse, NCHW store.
__global__ __launch_bounds__(256) void finalize_kernel(
    const float* __restrict__ psa, const float* __restrict__ bsa,
    const float* __restrict__ pda, const float* __restrict__ bda,
    const float* __restrict__ gsa, const float* __restrict__ gda,
    float* __restrict__ out, float* __restrict__ ws)
{
  __shared__ float sain[2][CDIM];
  __shared__ float dain[2][CDIM];
  __shared__ float cat[2][2 * CDIM];
  __shared__ float gl[2][2][CDIM];
  int i0 = blockIdx.x * 2, t = threadIdx.x;
  int h = t >> 7, c = t & 127;
  #pragma unroll
  for (int rr = 0; rr < 2; ++rr) {
    int i = i0 + rr;
    if (h == 0) {
      int row = (i & 3) * 128 + c;
      float s = ws[OFF_SUMS + row];
      sain[rr][c] = ws[OFF_OUT + row * CDIM + (i >> 2)] / s;
    } else {
      float s = ws[OFF_SUMS + 512 + i];
      dain[rr][c] = ws[OFF_OUT + NQ * CDIM + i * CDIM + c] / s;
    }
  }
  __syncthreads();
  {
    const float4* w4 = (const float4*)((h ? pda : psa) + c * CDIM);
    const float* in0 = h ? dain[0] : sain[0];
    const float* in1 = h ? dain[1] : sain[1];
    float a0 = 0, a1 = 0, b0 = 0, b1 = 0;
    #pragma unroll 8
    for (int j4 = 0; j4 < 32; ++j4) {
      float4 wv = w4[j4];
      float4 x0 = *(const float4*)&in0[j4 * 4];
      float4 x1 = *(const float4*)&in1[j4 * 4];
      a0 = fmaf(wv.x, x0.x, a0); a1 = fmaf(wv.y, x0.y, a1);
      a0 = fmaf(wv.z, x0.z, a0); a1 = fmaf(wv.w, x0.w, a1);
      b0 = fmaf(wv.x, x1.x, b0); b1 = fmaf(wv.y, x1.y, b1);
      b0 = fmaf(wv.z, x1.z, b0); b1 = fmaf(wv.w, x1.w, b1);
    }
    float bias = h ? bda[c] : bsa[c];
    cat[0][h * CDIM + c] = bias + a0 + a1;
    cat[1][h * CDIM + c] = bias + b0 + b1;
  }
  __syncthreads();
  {
    const float4* g4 = (const float4*)((h ? gda : gsa) + c * 2 * CDIM);
    float a0 = 0, a1 = 0, b0 = 0, b1 = 0;
    #pragma unroll 8
    for (int j4 = 0; j4 < 64; ++j4) {
      float4 gv = g4[j4];
      float4 c0 = *(const float4*)&cat[0][j4 * 4];
      float4 c1 = *(const float4*)&cat[1][j4 * 4];
      a0 = fmaf(gv.x, c0.x, a0); a1 = fmaf(gv.y, c0.y, a1);
      a0 = fmaf(gv.z, c0.z, a0); a1 = fmaf(gv.w, c0.w, a1);
      b0 = fmaf(gv.x, c1.x, b0); b1 = fmaf(gv.y, c1.y, b1);
      b0 = fmaf(gv.z, c1.z, b0); b1 = fmaf(gv.w, c1.w, b1);
    }
    gl[0][h][c] = 1.0f / (1.0f + __expf(-(a0 + a1)));
    gl[1][h][c] = 1.0f / (1.0f + __expf(-(b0 + b1)));
  }
  __syncthreads();
  {
    int i = i0 + h;
    out[c * NQ + i] = gl[h][0][c] * cat[h][c] + gl[h][1][c] * cat[h][CDIM + c];
  }
}

// ---------------------------------------------------------------- launch
extern "C" void kernel_launch(void* const* d_in, const int* in_sizes, int n_in,
                              void* d_out, int out_size, void* d_ws, size_t ws_size,
                              hipStream_t stream)
{
  (void)in_sizes; (void)n_in; (void)out_size; (void)ws_size;
  const float* erp       = (const float*)d_in[0];
  const float* ico       = (const float*)d_in[1];
  const float* coord     = (const float*)d_in[2];
  const float* wq_sa     = (const float*)d_in[3];
  const float* wkv_sa    = (const float*)d_in[4];
  const float* proj_sa_w = (const float*)d_in[5];
  const float* proj_sa_b = (const float*)d_in[6];
  const float* wq_da     = (const float*)d_in[7];
  const float* wkv_da    = (const float*)d_in[8];
  const float* wdelta    = (const float*)d_in[9];
  const float* proj_da_w = (const float*)d_in[10];
  const float* proj_da_b = (const float*)d_in[11];
  const float* gate_sa   = (const float*)d_in[12];
  const float* gate_da   = (const float*)d_in[13];
  float* out = (float*)d_out;
  float* ws  = (float*)d_ws;

  hipLaunchKernelGGL(prep_kernel, dim3(577), dim3(256), 0, stream,
                     erp, ico, wq_sa, wq_da, wkv_sa, wkv_da, wdelta, ws);
  hipLaunchKernelGGL(attn_kernel, dim3(1280), dim3(256), 0, stream,
                     coord, ws);
  hipLaunchKernelGGL(finalize_kernel, dim3(256), dim3(256), 0, stream,
                     proj_sa_w, proj_sa_b, proj_da_w, proj_da_b,
                     gate_sa, gate_da, out, ws);
}

// Round 5
// 142.733 us; speedup vs baseline: 1.1050x; 1.1050x over previous
//
#include <hip/hip_runtime.h>
#include <math.h>

#define NQ   512
#define NKV  1280
#define CDIM 128

// workspace layout (float offsets)
#define OFF_WDSUM 0        // 3
#define OFF_SUMS  16       // 1024: [br][512] row sums (zeroed by prep)
#define OFF_QSA   1056     // 65536 [n=512][c=128]
#define OFF_QDA   66592    // 65536
#define OFF_KSAT  132128   // 163840 [c=128][k=1280] transposed (coalesced score)
#define OFF_VSA   295968   // 163840 [k=1280][c=128] row-major (coalesced AV)
#define OFF_KDAT  459808   // 163840
#define OFF_VDA   623648   // 163840
#define OFF_OUT   787488   // 131072: [br][512][128] unnormalized AV (zeroed)
// total 918560 floats = 3.67 MB

// ---------------------------------------------------------------- prep
// bx<320: kv proj (4 keys); bx in [320,448): q proj (4 rows);
// bx==448: wdsum + zero sums; bx in [449,577): zero OUT.
__global__ __launch_bounds__(256) void prep_kernel(
    const float* __restrict__ erp, const float* __restrict__ ico,
    const float* __restrict__ wq_sa, const float* __restrict__ wq_da,
    const float* __restrict__ wkv_sa, const float* __restrict__ wkv_da,
    const float* __restrict__ wdelta, float* __restrict__ ws)
{
  int bx = blockIdx.x, t = threadIdx.x;
  if (bx < 320) {
    __shared__ float x4[4 * CDIM];          // [j*4 + ky]
    int k0 = bx * 4;
    for (int i = t; i < 512; i += 256) {
      int ky = i >> 7, j = i & 127;
      x4[j * 4 + ky] = ico[(k0 + ky) * CDIM + j];
    }
    __syncthreads();
    const float4* wsa4 = (const float4*)(wkv_sa + t * CDIM);
    const float4* wda4 = (const float4*)(wkv_da + t * CDIM);
    float as0=0,as1=0,as2=0,as3=0, ad0=0,ad1=0,ad2=0,ad3=0;
    #pragma unroll 4
    for (int j4 = 0; j4 < 32; ++j4) {
      float4 wsv = wsa4[j4];
      float4 wdv = wda4[j4];
      float4 x0 = *(const float4*)&x4[(j4 * 4 + 0) * 4];
      float4 x1 = *(const float4*)&x4[(j4 * 4 + 1) * 4];
      float4 x2 = *(const float4*)&x4[(j4 * 4 + 2) * 4];
      float4 x3 = *(const float4*)&x4[(j4 * 4 + 3) * 4];
      as0 = fmaf(wsv.x, x0.x, as0); as1 = fmaf(wsv.x, x0.y, as1);
      as2 = fmaf(wsv.x, x0.z, as2); as3 = fmaf(wsv.x, x0.w, as3);
      ad0 = fmaf(wdv.x, x0.x, ad0); ad1 = fmaf(wdv.x, x0.y, ad1);
      ad2 = fmaf(wdv.x, x0.z, ad2); ad3 = fmaf(wdv.x, x0.w, ad3);
      as0 = fmaf(wsv.y, x1.x, as0); as1 = fmaf(wsv.y, x1.y, as1);
      as2 = fmaf(wsv.y, x1.z, as2); as3 = fmaf(wsv.y, x1.w, as3);
      ad0 = fmaf(wdv.y, x1.x, ad0); ad1 = fmaf(wdv.y, x1.y, ad1);
      ad2 = fmaf(wdv.y, x1.z, ad2); ad3 = fmaf(wdv.y, x1.w, ad3);
      as0 = fmaf(wsv.z, x2.x, as0); as1 = fmaf(wsv.z, x2.y, as1);
      as2 = fmaf(wsv.z, x2.z, as2); as3 = fmaf(wsv.z, x2.w, as3);
      ad0 = fmaf(wdv.z, x2.x, ad0); ad1 = fmaf(wdv.z, x2.y, ad1);
      ad2 = fmaf(wdv.z, x2.z, ad2); ad3 = fmaf(wdv.z, x2.w, ad3);
      as0 = fmaf(wsv.w, x3.x, as0); as1 = fmaf(wsv.w, x3.y, as1);
      as2 = fmaf(wsv.w, x3.z, as2); as3 = fmaf(wsv.w, x3.w, as3);
      ad0 = fmaf(wdv.w, x3.x, ad0); ad1 = fmaf(wdv.w, x3.y, ad1);
      ad2 = fmaf(wdv.w, x3.z, ad2); ad3 = fmaf(wdv.w, x3.w, ad3);
    }
    if (t < 128) {   // k features -> transposed [c][k], float4 along k
      *(float4*)(ws + OFF_KSAT + t * NKV + k0) = make_float4(as0, as1, as2, as3);
      *(float4*)(ws + OFF_KDAT + t * NKV + k0) = make_float4(ad0, ad1, ad2, ad3);
    } else {         // v features -> [k][c] row-major (coalesced scalar stores)
      int c = t - 128;
      ws[OFF_VSA + (k0 + 0) * CDIM + c] = as0;
      ws[OFF_VSA + (k0 + 1) * CDIM + c] = as1;
      ws[OFF_VSA + (k0 + 2) * CDIM + c] = as2;
      ws[OFF_VSA + (k0 + 3) * CDIM + c] = as3;
      ws[OFF_VDA + (k0 + 0) * CDIM + c] = ad0;
      ws[OFF_VDA + (k0 + 1) * CDIM + c] = ad1;
      ws[OFF_VDA + (k0 + 2) * CDIM + c] = ad2;
      ws[OFF_VDA + (k0 + 3) * CDIM + c] = ad3;
    }
  } else if (bx < 448) {
    // q projection, 4 rows; t<128 -> q_sa out c=t, t>=128 -> q_da out c=t-128
    __shared__ float q4[4 * CDIM];          // [j*4 + r]
    int n0 = (bx - 320) * 4;
    for (int i = t; i < 512; i += 256)
      q4[i] = erp[(i >> 2) * NQ + n0 + (i & 3)];
    __syncthreads();
    const float* w = (t < 128) ? wq_sa : wq_da;
    int c = t & 127;
    const float4* w4 = (const float4*)(w + c * CDIM);
    float a0 = 0.f, a1 = 0.f, a2 = 0.f, a3 = 0.f;
    #pragma unroll 8
    for (int j4 = 0; j4 < 32; ++j4) {
      float4 wv = w4[j4];
      float4 q0 = *(const float4*)&q4[(j4 * 4 + 0) * 4];
      float4 q1 = *(const float4*)&q4[(j4 * 4 + 1) * 4];
      float4 q2 = *(const float4*)&q4[(j4 * 4 + 2) * 4];
      float4 q3 = *(const float4*)&q4[(j4 * 4 + 3) * 4];
      a0 = fmaf(wv.x, q0.x, a0); a1 = fmaf(wv.x, q0.y, a1);
      a2 = fmaf(wv.x, q0.z, a2); a3 = fmaf(wv.x, q0.w, a3);
      a0 = fmaf(wv.y, q1.x, a0); a1 = fmaf(wv.y, q1.y, a1);
      a2 = fmaf(wv.y, q1.z, a2); a3 = fmaf(wv.y, q1.w, a3);
      a0 = fmaf(wv.z, q2.x, a0); a1 = fmaf(wv.z, q2.y, a1);
      a2 = fmaf(wv.z, q2.z, a2); a3 = fmaf(wv.z, q2.w, a3);
      a0 = fmaf(wv.w, q3.x, a0); a1 = fmaf(wv.w, q3.y, a1);
      a2 = fmaf(wv.w, q3.z, a2); a3 = fmaf(wv.w, q3.w, a3);
    }
    float* o = ws + ((t < 128) ? OFF_QSA : OFF_QDA);
    o[(n0 + 0) * CDIM + c] = a0;
    o[(n0 + 1) * CDIM + c] = a1;
    o[(n0 + 2) * CDIM + c] = a2;
    o[(n0 + 3) * CDIM + c] = a3;
  } else if (bx == 448) {
    *(float4*)(ws + OFF_SUMS + t * 4) = make_float4(0.f, 0.f, 0.f, 0.f);
    if (t < 3) {   // Wdelta.sum(0)
      float s = 0.f;
      for (int i = 0; i < 128; ++i) s += wdelta[i * 3 + t];
      ws[OFF_WDSUM + t] = s;
    }
  } else {
    int base = OFF_OUT + (bx - 449) * 1024 + t * 4;
    *(float4*)(ws + base) = make_float4(0.f, 0.f, 0.f, 0.f);
  }
}

// ---------------------------------------------------------------- attn
// 1920 blocks, da FIRST (b<1280: long blocks), sa after (b>=1280: short).
// da block: 4 rows x 128 keys (g=b/10, z=b%10). Thread = (key t&127,
//   row-pair t>>7): 2 exp-chains over 128 j, 8-deep batched K loads
//   (lane-contiguous 4B; half-waves duplicate -> L1 hit).
// sa block: 4 rows x 256 keys (g=bb/5, z=bb%5). Thread owns key t, 4 FMA
//   chains, 4-deep batched loads.
// Row sums via wave shuffle -> red -> atomicAdd. AV: thread (c,half) over
// its k-half, 4 rows; V[k][c] lane-contiguous, se float4 broadcasts.
__global__ __launch_bounds__(256) void attn_kernel(
    const float* __restrict__ coord, float* __restrict__ ws)
{
  __shared__ __align__(16) float qjf[128][4];  // [j][r] 2KB
  __shared__ __align__(16) float se[4][256];   // exp(logit); da uses [..][0:128]
  __shared__ float red[4][4];
  __shared__ float qcr[4][3];
  __shared__ float wdl[3];
  int b = blockIdx.x, t = threadIdx.x;
  int br = (b < 1280) ? 1 : 0;     // da dispatched first
  int n0, k0;
  if (br) { int g = b / 10;          n0 = g * 4; k0 = (b - g * 10) * 128; }
  else    { int bb = b - 1280, g = bb / 5; n0 = g * 4; k0 = (bb - g * 5) * 256; }

  const float* qsrc = ws + (br ? OFF_QDA : OFF_QSA);
  for (int i = t; i < 512; i += 256)
    qjf[i >> 2][i & 3] = qsrc[(n0 + (i & 3)) * CDIM + (i >> 2)];
  if (br) {
    if (t < 4) {
      int n = n0 + t;
      float x = (float)(n & 31), y = (float)(n >> 5);
      float u  = (x - 16.5f) * 0.19634954084936207f;  // pi/16
      float vv = (y -  8.5f) * 0.19634954084936207f;
      float cv = cosf(vv);
      qcr[t][0] = cv * sinf(u);
      qcr[t][1] = sinf(vv);
      qcr[t][2] = cv * cosf(u);
    }
    if (t >= 64 && t < 67) wdl[t - 64] = ws[OFF_WDSUM + (t - 64)];
  }
  __syncthreads();

  if (br) {
    // ---- da score: thread = (key kl, row-pair rp) -> rows 2rp, 2rp+1
    int kl = t & 127, rp = t >> 7;
    int k = k0 + kl, rp2 = rp * 2;
    // pos_aff first so coord loads issue early
    float c0 = coord[3 * k], c1 = coord[3 * k + 1], c2 = coord[3 * k + 2];
    float w0 = wdl[0], w1 = wdl[1], w2 = wdl[2];
    float pA = w0 * __expf(-fabsf(qcr[rp2][0] - c0))
             + w1 * __expf(-fabsf(qcr[rp2][1] - c1))
             + w2 * __expf(-fabsf(qcr[rp2][2] - c2));
    float pB = w0 * __expf(-fabsf(qcr[rp2 + 1][0] - c0))
             + w1 * __expf(-fabsf(qcr[rp2 + 1][1] - c1))
             + w2 * __expf(-fabsf(qcr[rp2 + 1][2] - c2));
    const float* kt = ws + OFF_KDAT + k;
    float accA = 0.f, accB = 0.f;
    for (int j8 = 0; j8 < 128; j8 += 8) {
      float kv0 = kt[(j8 + 0) * NKV];
      float kv1 = kt[(j8 + 1) * NKV];
      float kv2 = kt[(j8 + 2) * NKV];
      float kv3 = kt[(j8 + 3) * NKV];
      float kv4 = kt[(j8 + 4) * NKV];
      float kv5 = kt[(j8 + 5) * NKV];
      float kv6 = kt[(j8 + 6) * NKV];
      float kv7 = kt[(j8 + 7) * NKV];
      float2 q0 = *(const float2*)&qjf[j8 + 0][rp2];
      float2 q1 = *(const float2*)&qjf[j8 + 1][rp2];
      float2 q2 = *(const float2*)&qjf[j8 + 2][rp2];
      float2 q3 = *(const float2*)&qjf[j8 + 3][rp2];
      float2 q4 = *(const float2*)&qjf[j8 + 4][rp2];
      float2 q5 = *(const float2*)&qjf[j8 + 5][rp2];
      float2 q6 = *(const float2*)&qjf[j8 + 6][rp2];
      float2 q7 = *(const float2*)&qjf[j8 + 7][rp2];
      accA += __expf(-fabsf(q0.x - kv0)); accB += __expf(-fabsf(q0.y - kv0));
      accA += __expf(-fabsf(q1.x - kv1)); accB += __expf(-fabsf(q1.y - kv1));
      accA += __expf(-fabsf(q2.x - kv2)); accB += __expf(-fabsf(q2.y - kv2));
      accA += __expf(-fabsf(q3.x - kv3)); accB += __expf(-fabsf(q3.y - kv3));
      accA += __expf(-fabsf(q4.x - kv4)); accB += __expf(-fabsf(q4.y - kv4));
      accA += __expf(-fabsf(q5.x - kv5)); accB += __expf(-fabsf(q5.y - kv5));
      accA += __expf(-fabsf(q6.x - kv6)); accB += __expf(-fabsf(q6.y - kv6));
      accA += __expf(-fabsf(q7.x - kv7)); accB += __expf(-fabsf(q7.y - kv7));
    }
    const float i128 = 0.0078125f;    // 1/C
    float eA = __expf((accA + pA) * i128);
    float eB = __expf((accB + pB) * i128);
    se[rp2][kl]     = eA;
    se[rp2 + 1][kl] = eB;
    // per-wave sums: wave w covers rows (2rp,2rp+1) x 64-key half
    float sA = eA, sB = eB;
    #pragma unroll
    for (int o = 32; o > 0; o >>= 1) {
      sA += __shfl_down(sA, o, 64); sB += __shfl_down(sB, o, 64);
    }
    if ((t & 63) == 0) { int w = t >> 6; red[w][0] = sA; red[w][1] = sB; }
    __syncthreads();   // covers se[] and red[]
    if (t < 4) {
      int base = 2 * (t >> 1);   // waves 0,1 -> rows 0,1; waves 2,3 -> rows 2,3
      atomicAdd(ws + OFF_SUMS + 512 + n0 + t,
                red[base][t & 1] + red[base + 1][t & 1]);
    }
    // ---- da AV: thread (c, half) -> 64-key half, 4 rows
    int c = t & 127, h = t >> 7;
    int kb = h * 64;
    const float* vp = ws + OFF_VDA + (k0 + kb) * CDIM + c;
    float a0 = 0.f, a1 = 0.f, a2 = 0.f, a3 = 0.f;
    #pragma unroll 2
    for (int ko = 0; ko < 64; ko += 4) {
      int kk = kb + ko;
      float4 p0 = *(const float4*)&se[0][kk];
      float4 p1 = *(const float4*)&se[1][kk];
      float4 p2 = *(const float4*)&se[2][kk];
      float4 p3 = *(const float4*)&se[3][kk];
      float v0 = vp[(ko + 0) * CDIM];
      float v1 = vp[(ko + 1) * CDIM];
      float v2 = vp[(ko + 2) * CDIM];
      float v3 = vp[(ko + 3) * CDIM];
      a0 = fmaf(p0.x, v0, a0); a0 = fmaf(p0.y, v1, a0);
      a0 = fmaf(p0.z, v2, a0); a0 = fmaf(p0.w, v3, a0);
      a1 = fmaf(p1.x, v0, a1); a1 = fmaf(p1.y, v1, a1);
      a1 = fmaf(p1.z, v2, a1); a1 = fmaf(p1.w, v3, a1);
      a2 = fmaf(p2.x, v0, a2); a2 = fmaf(p2.y, v1, a2);
      a2 = fmaf(p2.z, v2, a2); a2 = fmaf(p2.w, v3, a2);
      a3 = fmaf(p3.x, v0, a3); a3 = fmaf(p3.y, v1, a3);
      a3 = fmaf(p3.z, v2, a3); a3 = fmaf(p3.w, v3, a3);
    }
    float* op = ws + OFF_OUT + NQ * CDIM + c;
    atomicAdd(op + (n0 + 0) * CDIM, a0);
    atomicAdd(op + (n0 + 1) * CDIM, a1);
    atomicAdd(op + (n0 + 2) * CDIM, a2);
    atomicAdd(op + (n0 + 3) * CDIM, a3);
  } else {
    // ---- sa score: thread owns key k0+t, 4 rows, 4-deep batched loads
    const float* kt = ws + OFF_KSAT + k0 + t;
    float acc0 = 0.f, acc1 = 0.f, acc2 = 0.f, acc3 = 0.f;
    for (int j4 = 0; j4 < 128; j4 += 4) {
      float kv0 = kt[(j4 + 0) * NKV];
      float kv1 = kt[(j4 + 1) * NKV];
      float kv2 = kt[(j4 + 2) * NKV];
      float kv3 = kt[(j4 + 3) * NKV];
      float4 q0 = *(const float4*)qjf[j4 + 0];
      float4 q1 = *(const float4*)qjf[j4 + 1];
      float4 q2 = *(const float4*)qjf[j4 + 2];
      float4 q3 = *(const float4*)qjf[j4 + 3];
      acc0 = fmaf(q0.x, kv0, acc0); acc1 = fmaf(q0.y, kv0, acc1);
      acc2 = fmaf(q0.z, kv0, acc2); acc3 = fmaf(q0.w, kv0, acc3);
      acc0 = fmaf(q1.x, kv1, acc0); acc1 = fmaf(q1.y, kv1, acc1);
      acc2 = fmaf(q1.z, kv1, acc2); acc3 = fmaf(q1.w, kv1, acc3);
      acc0 = fmaf(q2.x, kv2, acc0); acc1 = fmaf(q2.y, kv2, acc1);
      acc2 = fmaf(q2.z, kv2, acc2); acc3 = fmaf(q2.w, kv2, acc3);
      acc0 = fmaf(q3.x, kv3, acc0); acc1 = fmaf(q3.y, kv3, acc1);
      acc2 = fmaf(q3.z, kv3, acc2); acc3 = fmaf(q3.w, kv3, acc3);
    }
    const float scl = 0.088388347648318447f;  // 128^-0.5
    float e0 = __expf(acc0 * scl);
    float e1 = __expf(acc1 * scl);
    float e2 = __expf(acc2 * scl);
    float e3 = __expf(acc3 * scl);
    se[0][t] = e0; se[1][t] = e1; se[2][t] = e2; se[3][t] = e3;
    float s0 = e0, s1 = e1, s2 = e2, s3 = e3;
    #pragma unroll
    for (int o = 32; o > 0; o >>= 1) {
      s0 += __shfl_down(s0, o, 64); s1 += __shfl_down(s1, o, 64);
      s2 += __shfl_down(s2, o, 64); s3 += __shfl_down(s3, o, 64);
    }
    if ((t & 63) == 0) {
      int w = t >> 6;
      red[w][0] = s0; red[w][1] = s1; red[w][2] = s2; red[w][3] = s3;
    }
    __syncthreads();   // covers se[] and red[]
    if (t < 4)
      atomicAdd(ws + OFF_SUMS + n0 + t,
                red[0][t] + red[1][t] + red[2][t] + red[3][t]);
    // ---- sa AV: thread (c, half) -> 128-key half, 4 rows
    int c = t & 127, h = t >> 7;
    int kb = h * 128;
    const float* vp = ws + OFF_VSA + (k0 + kb) * CDIM + c;
    float a0 = 0.f, a1 = 0.f, a2 = 0.f, a3 = 0.f;
    #pragma unroll 2
    for (int ko = 0; ko < 128; ko += 4) {
      int kk = kb + ko;
      float4 p0 = *(const float4*)&se[0][kk];
      float4 p1 = *(const float4*)&se[1][kk];
      float4 p2 = *(const float4*)&se[2][kk];
      float4 p3 = *(const float4*)&se[3][kk];
      float v0 = vp[(ko + 0) * CDIM];
      float v1 = vp[(ko + 1) * CDIM];
      float v2 = vp[(ko + 2) * CDIM];
      float v3 = vp[(ko + 3) * CDIM];
      a0 = fmaf(p0.x, v0, a0); a0 = fmaf(p0.y, v1, a0);
      a0 = fmaf(p0.z, v2, a0); a0 = fmaf(p0.w, v3, a0);
      a1 = fmaf(p1.x, v0, a1); a1 = fmaf(p1.y, v1, a1);
      a1 = fmaf(p1.z, v2, a1); a1 = fmaf(p1.w, v3, a1);
      a2 = fmaf(p2.x, v0, a2); a2 = fmaf(p2.y, v1, a2);
      a2 = fmaf(p2.z, v2, a2); a2 = fmaf(p2.w, v3, a2);
      a3 = fmaf(p3.x, v0, a3); a3 = fmaf(p3.y, v1, a3);
      a3 = fmaf(p3.z, v2, a3); a3 = fmaf(p3.w, v3, a3);
    }
    float* op = ws + OFF_OUT + c;
    atomicAdd(op + (n0 + 0) * CDIM, a0);
    atomicAdd(op + (n0 + 1) * CDIM, a1);
    atomicAdd(op + (n0 + 2) * CDIM, a2);
    atomicAdd(op + (n0 + 3) * CDIM, a3);
  }
}

// ---------------------------------------------------------------- finalize
// one block (256 thr) per 2 query rows: normalize (divide by sums) with the
// reference's transpose-reshape on sa, project both, gate, fuse, NCHW store.
__global__ __launch_bounds__(256) void finalize_kernel(
    const float* __restrict__ psa, const float* __restrict__ bsa,
    const float* __restrict__ pda, const float* __restrict__ bda,
    const float* __restrict__ gsa, const float* __restrict__ gda,
    float* __restrict__ out, float* __restrict__ ws)
{
  __shared__ float sain[2][CDIM];
  __shared__ float dain[2][CDIM];
  __shared__ float cat[2][2 * CDIM];
  __shared__ float gl[2][2][CDIM];
  int i0 = blockIdx.x * 2, t = threadIdx.x;
  int h = t >> 7, c = t & 127;
  #pragma unroll
  for (int rr = 0; rr < 2; ++rr) {
    int i = i0 + rr;
    if (h == 0) {
      int row = (i & 3) * 128 + c;
      float s = ws[OFF_SUMS + row];
      sain[rr][c] = ws[OFF_OUT + row * CDIM + (i >> 2)] / s;
    } else {
      float s = ws[OFF_SUMS + 512 + i];
      dain[rr][c] = ws[OFF_OUT + NQ * CDIM + i * CDIM + c] / s;
    }
  }
  __syncthreads();
  {
    const float4* w4 = (const float4*)((h ? pda : psa) + c * CDIM);
    const float* in0 = h ? dain[0] : sain[0];
    const float* in1 = h ? dain[1] : sain[1];
    float a0 = 0, a1 = 0, b0 = 0, b1 = 0;
    #pragma unroll 8
    for (int j4 = 0; j4 < 32; ++j4) {
      float4 wv = w4[j4];
      float4 x0 = *(const float4*)&in0[j4 * 4];
      float4 x1 = *(const float4*)&in1[j4 * 4];
      a0 = fmaf(wv.x, x0.x, a0); a1 = fmaf(wv.y, x0.y, a1);
      a0 = fmaf(wv.z, x0.z, a0); a1 = fmaf(wv.w, x0.w, a1);
      b0 = fmaf(wv.x, x1.x, b0); b1 = fmaf(wv.y, x1.y, b1);
      b0 = fmaf(wv.z, x1.z, b0); b1 = fmaf(wv.w, x1.w, b1);
    }
    float bias = h ? bda[c] : bsa[c];
    cat[0][h * CDIM + c] = bias + a0 + a1;
    cat[1][h * CDIM + c] = bias + b0 + b1;
  }
  __syncthreads();
  {
    const float4* g4 = (const float4*)((h ? gda : gsa) + c * 2 * CDIM);
    float a0 = 0, a1 = 0, b0 = 0, b1 = 0;
    #pragma unroll 8
    for (int j4 = 0; j4 < 64; ++j4) {
      float4 gv = g4[j4];
      float4 c0 = *(const float4*)&cat[0][j4 * 4];
      float4 c1 = *(const float4*)&cat[1][j4 * 4];
      a0 = fmaf(gv.x, c0.x, a0); a1 = fmaf(gv.y, c0.y, a1);
      a0 = fmaf(gv.z, c0.z, a0); a1 = fmaf(gv.w, c0.w, a1);
      b0 = fmaf(gv.x, c1.x, b0); b1 = fmaf(gv.y, c1.y, b1);
      b0 = fmaf(gv.z, c1.z, b0); b1 = fmaf(gv.w, c1.w, b1);
    }
    gl[0][h][c] = 1.0f / (1.0f + __expf(-(a0 + a1)));
    gl[1][h][c] = 1.0f / (1.0f + __expf(-(b0 + b1)));
  }
  __syncthreads();
  {
    int i = i0 + h;
    out[c * NQ + i] = gl[h][0][c] * cat[h][c] + gl[h][1][c] * cat[h][CDIM + c];
  }
}

// ---------------------------------------------------------------- launch
extern "C" void kernel_launch(void* const* d_in, const int* in_sizes, int n_in,
                              void* d_out, int out_size, void* d_ws, size_t ws_size,
                              hipStream_t stream)
{
  (void)in_sizes; (void)n_in; (void)out_size; (void)ws_size;
  const float* erp       = (const float*)d_in[0];
  const float* ico       = (const float*)d_in[1];
  const float* coord     = (const float*)d_in[2];
  const float* wq_sa     = (const float*)d_in[3];
  const float* wkv_sa    = (const float*)d_in[4];
  const float* proj_sa_w = (const float*)d_in[5];
  const float* proj_sa_b = (const float*)d_in[6];
  const float* wq_da     = (const float*)d_in[7];
  const float* wkv_da    = (const float*)d_in[8];
  const float* wdelta    = (const float*)d_in[9];
  const float* proj_da_w = (const float*)d_in[10];
  const float* proj_da_b = (const float*)d_in[11];
  const float* gate_sa   = (const float*)d_in[12];
  const float* gate_da   = (const float*)d_in[13];
  float* out = (float*)d_out;
  float* ws  = (float*)d_ws;

  hipLaunchKernelGGL(prep_kernel, dim3(577), dim3(256), 0, stream,
                     erp, ico, wq_sa, wq_da, wkv_sa, wkv_da, wdelta, ws);
  hipLaunchKernelGGL(attn_kernel, dim3(1920), dim3(256), 0, stream,
                     coord, ws);
  hipLaunchKernelGGL(finalize_kernel, dim3(256), dim3(256), 0, stream,
                     proj_sa_w, proj_sa_b, proj_da_w, proj_da_b,
                     gate_sa, gate_da, out, ws);
}

// Round 6
// 138.207 us; speedup vs baseline: 1.1412x; 1.0327x over previous
//
#include <hip/hip_runtime.h>
#include <math.h>

#define NQ   512
#define NKV  1280
#define CDIM 128
#define L2E  1.4426950408889634f

__device__ __forceinline__ float fexp2(float x) { return __builtin_amdgcn_exp2f(x); }

// workspace layout (float offsets)
#define OFF_WDSUM 0        // 3
#define OFF_SUMS  16       // 1024: [br][512] row sums (zeroed by prep)
#define OFF_QSA   1056     // 65536 [n=512][c=128]
#define OFF_QDA   66592    // 65536 (scaled by log2e)
#define OFF_KSAT  132128   // 163840 [c=128][k=1280] transposed (coalesced score)
#define OFF_VSA   295968   // 163840 [k=1280][c=128] row-major (coalesced AV)
#define OFF_KDAT  459808   // 163840 (scaled by log2e)
#define OFF_VDA   623648   // 163840 (unscaled)
#define OFF_OUT   787488   // 131072: [br][512][128] unnormalized AV (zeroed)
// total 918560 floats = 3.67 MB

// ---------------------------------------------------------------- prep
// bx<320: kv proj (4 keys); bx in [320,448): q proj (4 rows);
// bx==448: wdsum + zero sums; bx in [449,577): zero OUT.
__global__ __launch_bounds__(256) void prep_kernel(
    const float* __restrict__ erp, const float* __restrict__ ico,
    const float* __restrict__ wq_sa, const float* __restrict__ wq_da,
    const float* __restrict__ wkv_sa, const float* __restrict__ wkv_da,
    const float* __restrict__ wdelta, float* __restrict__ ws)
{
  int bx = blockIdx.x, t = threadIdx.x;
  if (bx < 320) {
    __shared__ float x4[4 * CDIM];          // [j*4 + ky]
    int k0 = bx * 4;
    for (int i = t; i < 512; i += 256) {
      int ky = i >> 7, j = i & 127;
      x4[j * 4 + ky] = ico[(k0 + ky) * CDIM + j];
    }
    __syncthreads();
    const float4* wsa4 = (const float4*)(wkv_sa + t * CDIM);
    const float4* wda4 = (const float4*)(wkv_da + t * CDIM);
    float as0=0,as1=0,as2=0,as3=0, ad0=0,ad1=0,ad2=0,ad3=0;
    #pragma unroll 4
    for (int j4 = 0; j4 < 32; ++j4) {
      float4 wsv = wsa4[j4];
      float4 wdv = wda4[j4];
      float4 x0 = *(const float4*)&x4[(j4 * 4 + 0) * 4];
      float4 x1 = *(const float4*)&x4[(j4 * 4 + 1) * 4];
      float4 x2 = *(const float4*)&x4[(j4 * 4 + 2) * 4];
      float4 x3 = *(const float4*)&x4[(j4 * 4 + 3) * 4];
      as0 = fmaf(wsv.x, x0.x, as0); as1 = fmaf(wsv.x, x0.y, as1);
      as2 = fmaf(wsv.x, x0.z, as2); as3 = fmaf(wsv.x, x0.w, as3);
      ad0 = fmaf(wdv.x, x0.x, ad0); ad1 = fmaf(wdv.x, x0.y, ad1);
      ad2 = fmaf(wdv.x, x0.z, ad2); ad3 = fmaf(wdv.x, x0.w, ad3);
      as0 = fmaf(wsv.y, x1.x, as0); as1 = fmaf(wsv.y, x1.y, as1);
      as2 = fmaf(wsv.y, x1.z, as2); as3 = fmaf(wsv.y, x1.w, as3);
      ad0 = fmaf(wdv.y, x1.x, ad0); ad1 = fmaf(wdv.y, x1.y, ad1);
      ad2 = fmaf(wdv.y, x1.z, ad2); ad3 = fmaf(wdv.y, x1.w, ad3);
      as0 = fmaf(wsv.z, x2.x, as0); as1 = fmaf(wsv.z, x2.y, as1);
      as2 = fmaf(wsv.z, x2.z, as2); as3 = fmaf(wsv.z, x2.w, as3);
      ad0 = fmaf(wdv.z, x2.x, ad0); ad1 = fmaf(wdv.z, x2.y, ad1);
      ad2 = fmaf(wdv.z, x2.z, ad2); ad3 = fmaf(wdv.z, x2.w, ad3);
      as0 = fmaf(wsv.w, x3.x, as0); as1 = fmaf(wsv.w, x3.y, as1);
      as2 = fmaf(wsv.w, x3.z, as2); as3 = fmaf(wsv.w, x3.w, as3);
      ad0 = fmaf(wdv.w, x3.x, ad0); ad1 = fmaf(wdv.w, x3.y, ad1);
      ad2 = fmaf(wdv.w, x3.z, ad2); ad3 = fmaf(wdv.w, x3.w, ad3);
    }
    if (t < 128) {   // k features -> transposed [c][k]; da scaled by log2e
      *(float4*)(ws + OFF_KSAT + t * NKV + k0) = make_float4(as0, as1, as2, as3);
      *(float4*)(ws + OFF_KDAT + t * NKV + k0) =
          make_float4(ad0 * L2E, ad1 * L2E, ad2 * L2E, ad3 * L2E);
    } else {         // v features -> [k][c] row-major (unscaled)
      int c = t - 128;
      ws[OFF_VSA + (k0 + 0) * CDIM + c] = as0;
      ws[OFF_VSA + (k0 + 1) * CDIM + c] = as1;
      ws[OFF_VSA + (k0 + 2) * CDIM + c] = as2;
      ws[OFF_VSA + (k0 + 3) * CDIM + c] = as3;
      ws[OFF_VDA + (k0 + 0) * CDIM + c] = ad0;
      ws[OFF_VDA + (k0 + 1) * CDIM + c] = ad1;
      ws[OFF_VDA + (k0 + 2) * CDIM + c] = ad2;
      ws[OFF_VDA + (k0 + 3) * CDIM + c] = ad3;
    }
  } else if (bx < 448) {
    // q projection, 4 rows; t<128 -> q_sa out c=t, t>=128 -> q_da (log2e-scaled)
    __shared__ float q4[4 * CDIM];          // [j*4 + r]
    int n0 = (bx - 320) * 4;
    for (int i = t; i < 512; i += 256)
      q4[i] = erp[(i >> 2) * NQ + n0 + (i & 3)];
    __syncthreads();
    const float* w = (t < 128) ? wq_sa : wq_da;
    int c = t & 127;
    const float4* w4 = (const float4*)(w + c * CDIM);
    float a0 = 0.f, a1 = 0.f, a2 = 0.f, a3 = 0.f;
    #pragma unroll 8
    for (int j4 = 0; j4 < 32; ++j4) {
      float4 wv = w4[j4];
      float4 q0 = *(const float4*)&q4[(j4 * 4 + 0) * 4];
      float4 q1 = *(const float4*)&q4[(j4 * 4 + 1) * 4];
      float4 q2 = *(const float4*)&q4[(j4 * 4 + 2) * 4];
      float4 q3 = *(const float4*)&q4[(j4 * 4 + 3) * 4];
      a0 = fmaf(wv.x, q0.x, a0); a1 = fmaf(wv.x, q0.y, a1);
      a2 = fmaf(wv.x, q0.z, a2); a3 = fmaf(wv.x, q0.w, a3);
      a0 = fmaf(wv.y, q1.x, a0); a1 = fmaf(wv.y, q1.y, a1);
      a2 = fmaf(wv.y, q1.z, a2); a3 = fmaf(wv.y, q1.w, a3);
      a0 = fmaf(wv.z, q2.x, a0); a1 = fmaf(wv.z, q2.y, a1);
      a2 = fmaf(wv.z, q2.z, a2); a3 = fmaf(wv.z, q2.w, a3);
      a0 = fmaf(wv.w, q3.x, a0); a1 = fmaf(wv.w, q3.y, a1);
      a2 = fmaf(wv.w, q3.z, a2); a3 = fmaf(wv.w, q3.w, a3);
    }
    float sc = (t < 128) ? 1.0f : L2E;
    float* o = ws + ((t < 128) ? OFF_QSA : OFF_QDA);
    o[(n0 + 0) * CDIM + c] = a0 * sc;
    o[(n0 + 1) * CDIM + c] = a1 * sc;
    o[(n0 + 2) * CDIM + c] = a2 * sc;
    o[(n0 + 3) * CDIM + c] = a3 * sc;
  } else if (bx == 448) {
    *(float4*)(ws + OFF_SUMS + t * 4) = make_float4(0.f, 0.f, 0.f, 0.f);
    if (t < 3) {   // Wdelta.sum(0)
      float s = 0.f;
      for (int i = 0; i < 128; ++i) s += wdelta[i * 3 + t];
      ws[OFF_WDSUM + t] = s;
    }
  } else {
    int base = OFF_OUT + (bx - 449) * 1024 + t * 4;
    *(float4*)(ws + base) = make_float4(0.f, 0.f, 0.f, 0.f);
  }
}

// ---------------------------------------------------------------- attn
// 1920 blocks, da FIRST (b<1280: long blocks), sa after (b>=1280: short).
// da block: 4 rows x 128 keys. K^T staged in double-buffered 16x128 LDS
//   chunks (coalesced float4; next-chunk loads issued before compute ->
//   latency hidden). Thread = (key kl, row-pair rp): 2 exp2 chains, all
//   inputs pre-scaled by log2e -> v_sub + v_exp(-|x|) + v_add per element.
// sa block: 4 rows x 256 keys, thread owns key, direct 4-deep batched loads.
// Row sums via wave shuffle -> red -> atomicAdd. AV: thread (c,half) over
// its k-half, 4 rows; V[k][c] lane-contiguous, se float4 broadcasts.
__global__ __launch_bounds__(256) void attn_kernel(
    const float* __restrict__ coord, float* __restrict__ ws)
{
  __shared__ __align__(16) float qjf[128][4];     // [j][r] 2KB
  __shared__ __align__(16) float se[4][256];      // exp(logit); da uses [0:128]
  __shared__ __align__(16) float kch[2][16][128]; // da K chunks, 16KB
  __shared__ float red[4][4];
  __shared__ float qcr[4][3];                     // log2e-scaled
  __shared__ float wdl[3];
  int b = blockIdx.x, t = threadIdx.x;
  int br = (b < 1280) ? 1 : 0;     // da dispatched first
  int n0, k0;
  if (br) { int g = b / 10;          n0 = g * 4; k0 = (b - g * 10) * 128; }
  else    { int bb = b - 1280, g = bb / 5; n0 = g * 4; k0 = (bb - g * 5) * 256; }

  const float* qsrc = ws + (br ? OFF_QDA : OFF_QSA);
  for (int i = t; i < 512; i += 256)
    qjf[i >> 2][i & 3] = qsrc[(n0 + (i & 3)) * CDIM + (i >> 2)];
  if (br) {
    if (t < 4) {
      int n = n0 + t;
      float x = (float)(n & 31), y = (float)(n >> 5);
      float u  = (x - 16.5f) * 0.19634954084936207f;  // pi/16
      float vv = (y -  8.5f) * 0.19634954084936207f;
      float cv = cosf(vv);
      qcr[t][0] = cv * sinf(u) * L2E;
      qcr[t][1] = sinf(vv) * L2E;
      qcr[t][2] = cv * cosf(u) * L2E;
    }
    if (t >= 64 && t < 67) wdl[t - 64] = ws[OFF_WDSUM + (t - 64)];
  }
  __syncthreads();

  if (br) {
    // ---- da score: thread = (key kl, row-pair rp) -> rows 2rp, 2rp+1
    int kl = t & 127, rp = t >> 7;
    int k = k0 + kl, rp2 = rp * 2;
    // pos_aff first so coord loads issue early (all log2e-scaled)
    float c0 = coord[3 * k]     * L2E;
    float c1 = coord[3 * k + 1] * L2E;
    float c2 = coord[3 * k + 2] * L2E;
    float w0 = wdl[0], w1 = wdl[1], w2 = wdl[2];
    float pA = w0 * fexp2(-fabsf(qcr[rp2][0] - c0))
             + w1 * fexp2(-fabsf(qcr[rp2][1] - c1))
             + w2 * fexp2(-fabsf(qcr[rp2][2] - c2));
    float pB = w0 * fexp2(-fabsf(qcr[rp2 + 1][0] - c0))
             + w1 * fexp2(-fabsf(qcr[rp2 + 1][1] - c1))
             + w2 * fexp2(-fabsf(qcr[rp2 + 1][2] - c2));
    // staged K chunks: srow/scol cooperative mapping (coalesced float4)
    const float* kbase = ws + OFF_KDAT + k0;
    int srow = t >> 5;          // 0..7 (row within chunk; +8 second pass)
    int scol = (t & 31) * 4;    // float col 0,4,...,124
    *(float4*)&kch[0][srow][scol] =
        *(const float4*)(kbase + (srow) * NKV + scol);
    *(float4*)&kch[0][srow + 8][scol] =
        *(const float4*)(kbase + (srow + 8) * NKV + scol);
    __syncthreads();
    float accA = 0.f, accB = 0.f;
    int cur = 0;
    for (int jb = 0; jb < 128; jb += 16) {
      float4 nx0, nx1;
      bool more = (jb + 16) < 128;
      if (more) {   // issue next-chunk loads BEFORE compute (latency hides)
        nx0 = *(const float4*)(kbase + (jb + 16 + srow) * NKV + scol);
        nx1 = *(const float4*)(kbase + (jb + 24 + srow) * NKV + scol);
      }
      #pragma unroll
      for (int j2 = 0; j2 < 16; ++j2) {
        float kv = kch[cur][j2][kl];
        float2 q = *(const float2*)&qjf[jb + j2][rp2];
        accA += fexp2(-fabsf(q.x - kv));
        accB += fexp2(-fabsf(q.y - kv));
      }
      __syncthreads();            // all reads of kch[cur] done
      if (more) {
        *(float4*)&kch[cur ^ 1][srow][scol]     = nx0;
        *(float4*)&kch[cur ^ 1][srow + 8][scol] = nx1;
      }
      __syncthreads();            // next chunk visible
      cur ^= 1;
    }
    const float lsc = 0.0078125f * L2E;   // (1/C) * log2e
    float eA = fexp2((accA + pA) * lsc);
    float eB = fexp2((accB + pB) * lsc);
    se[rp2][kl]     = eA;
    se[rp2 + 1][kl] = eB;
    // per-wave sums: wave w covers rows (2rp,2rp+1) x 64-key half
    float sA = eA, sB = eB;
    #pragma unroll
    for (int o = 32; o > 0; o >>= 1) {
      sA += __shfl_down(sA, o, 64); sB += __shfl_down(sB, o, 64);
    }
    if ((t & 63) == 0) { int w = t >> 6; red[w][0] = sA; red[w][1] = sB; }
    __syncthreads();   // covers se[] and red[]
    if (t < 4) {
      int base = 2 * (t >> 1);   // waves 0,1 -> rows 0,1; waves 2,3 -> rows 2,3
      atomicAdd(ws + OFF_SUMS + 512 + n0 + t,
                red[base][t & 1] + red[base + 1][t & 1]);
    }
    // ---- da AV: thread (c, half) -> 64-key half, 4 rows
    int c = t & 127, h = t >> 7;
    int kb = h * 64;
    const float* vp = ws + OFF_VDA + (k0 + kb) * CDIM + c;
    float a0 = 0.f, a1 = 0.f, a2 = 0.f, a3 = 0.f;
    #pragma unroll 2
    for (int ko = 0; ko < 64; ko += 4) {
      int kk = kb + ko;
      float4 p0 = *(const float4*)&se[0][kk];
      float4 p1 = *(const float4*)&se[1][kk];
      float4 p2 = *(const float4*)&se[2][kk];
      float4 p3 = *(const float4*)&se[3][kk];
      float v0 = vp[(ko + 0) * CDIM];
      float v1 = vp[(ko + 1) * CDIM];
      float v2 = vp[(ko + 2) * CDIM];
      float v3 = vp[(ko + 3) * CDIM];
      a0 = fmaf(p0.x, v0, a0); a0 = fmaf(p0.y, v1, a0);
      a0 = fmaf(p0.z, v2, a0); a0 = fmaf(p0.w, v3, a0);
      a1 = fmaf(p1.x, v0, a1); a1 = fmaf(p1.y, v1, a1);
      a1 = fmaf(p1.z, v2, a1); a1 = fmaf(p1.w, v3, a1);
      a2 = fmaf(p2.x, v0, a2); a2 = fmaf(p2.y, v1, a2);
      a2 = fmaf(p2.z, v2, a2); a2 = fmaf(p2.w, v3, a2);
      a3 = fmaf(p3.x, v0, a3); a3 = fmaf(p3.y, v1, a3);
      a3 = fmaf(p3.z, v2, a3); a3 = fmaf(p3.w, v3, a3);
    }
    float* op = ws + OFF_OUT + NQ * CDIM + c;
    atomicAdd(op + (n0 + 0) * CDIM, a0);
    atomicAdd(op + (n0 + 1) * CDIM, a1);
    atomicAdd(op + (n0 + 2) * CDIM, a2);
    atomicAdd(op + (n0 + 3) * CDIM, a3);
  } else {
    // ---- sa score: thread owns key k0+t, 4 rows, 4-deep batched loads
    const float* kt = ws + OFF_KSAT + k0 + t;
    float acc0 = 0.f, acc1 = 0.f, acc2 = 0.f, acc3 = 0.f;
    for (int j4 = 0; j4 < 128; j4 += 4) {
      float kv0 = kt[(j4 + 0) * NKV];
      float kv1 = kt[(j4 + 1) * NKV];
      float kv2 = kt[(j4 + 2) * NKV];
      float kv3 = kt[(j4 + 3) * NKV];
      float4 q0 = *(const float4*)qjf[j4 + 0];
      float4 q1 = *(const float4*)qjf[j4 + 1];
      float4 q2 = *(const float4*)qjf[j4 + 2];
      float4 q3 = *(const float4*)qjf[j4 + 3];
      acc0 = fmaf(q0.x, kv0, acc0); acc1 = fmaf(q0.y, kv0, acc1);
      acc2 = fmaf(q0.z, kv0, acc2); acc3 = fmaf(q0.w, kv0, acc3);
      acc0 = fmaf(q1.x, kv1, acc0); acc1 = fmaf(q1.y, kv1, acc1);
      acc2 = fmaf(q1.z, kv1, acc2); acc3 = fmaf(q1.w, kv1, acc3);
      acc0 = fmaf(q2.x, kv2, acc0); acc1 = fmaf(q2.y, kv2, acc1);
      acc2 = fmaf(q2.z, kv2, acc2); acc3 = fmaf(q2.w, kv2, acc3);
      acc0 = fmaf(q3.x, kv3, acc0); acc1 = fmaf(q3.y, kv3, acc1);
      acc2 = fmaf(q3.z, kv3, acc2); acc3 = fmaf(q3.w, kv3, acc3);
    }
    const float scl2 = 0.088388347648318447f * L2E;  // C^-0.5 * log2e
    float e0 = fexp2(acc0 * scl2);
    float e1 = fexp2(acc1 * scl2);
    float e2 = fexp2(acc2 * scl2);
    float e3 = fexp2(acc3 * scl2);
    se[0][t] = e0; se[1][t] = e1; se[2][t] = e2; se[3][t] = e3;
    float s0 = e0, s1 = e1, s2 = e2, s3 = e3;
    #pragma unroll
    for (int o = 32; o > 0; o >>= 1) {
      s0 += __shfl_down(s0, o, 64); s1 += __shfl_down(s1, o, 64);
      s2 += __shfl_down(s2, o, 64); s3 += __shfl_down(s3, o, 64);
    }
    if ((t & 63) == 0) {
      int w = t >> 6;
      red[w][0] = s0; red[w][1] = s1; red[w][2] = s2; red[w][3] = s3;
    }
    __syncthreads();   // covers se[] and red[]
    if (t < 4)
      atomicAdd(ws + OFF_SUMS + n0 + t,
                red[0][t] + red[1][t] + red[2][t] + red[3][t]);
    // ---- sa AV: thread (c, half) -> 128-key half, 4 rows
    int c = t & 127, h = t >> 7;
    int kb = h * 128;
    const float* vp = ws + OFF_VSA + (k0 + kb) * CDIM + c;
    float a0 = 0.f, a1 = 0.f, a2 = 0.f, a3 = 0.f;
    #pragma unroll 2
    for (int ko = 0; ko < 128; ko += 4) {
      int kk = kb + ko;
      float4 p0 = *(const float4*)&se[0][kk];
      float4 p1 = *(const float4*)&se[1][kk];
      float4 p2 = *(const float4*)&se[2][kk];
      float4 p3 = *(const float4*)&se[3][kk];
      float v0 = vp[(ko + 0) * CDIM];
      float v1 = vp[(ko + 1) * CDIM];
      float v2 = vp[(ko + 2) * CDIM];
      float v3 = vp[(ko + 3) * CDIM];
      a0 = fmaf(p0.x, v0, a0); a0 = fmaf(p0.y, v1, a0);
      a0 = fmaf(p0.z, v2, a0); a0 = fmaf(p0.w, v3, a0);
      a1 = fmaf(p1.x, v0, a1); a1 = fmaf(p1.y, v1, a1);
      a1 = fmaf(p1.z, v2, a1); a1 = fmaf(p1.w, v3, a1);
      a2 = fmaf(p2.x, v0, a2); a2 = fmaf(p2.y, v1, a2);
      a2 = fmaf(p2.z, v2, a2); a2 = fmaf(p2.w, v3, a2);
      a3 = fmaf(p3.x, v0, a3); a3 = fmaf(p3.y, v1, a3);
      a3 = fmaf(p3.z, v2, a3); a3 = fmaf(p3.w, v3, a3);
    }
    float* op = ws + OFF_OUT + c;
    atomicAdd(op + (n0 + 0) * CDIM, a0);
    atomicAdd(op + (n0 + 1) * CDIM, a1);
    atomicAdd(op + (n0 + 2) * CDIM, a2);
    atomicAdd(op + (n0 + 3) * CDIM, a3);
  }
}

// ---------------------------------------------------------------- finalize
// one block (256 thr) per 2 query rows: normalize (divide by sums) with the
// reference's transpose-reshape on sa, project both, gate, fuse, NCHW store.
__global__ __launch_bounds__(256) void finalize_kernel(
    const float* __restrict__ psa, const float* __restrict__ bsa,
    const float* __restrict__ pda, const float* __restrict__ bda,
    const float* __restrict__ gsa, const float* __restrict__ gda,
    float* __restrict__ out, float* __restrict__ ws)
{
  __shared__ float sain[2][CDIM];
  __shared__ float dain[2][CDIM];
  __shared__ float cat[2][2 * CDIM];
  __shared__ float gl[2][2][CDIM];
  int i0 = blockIdx.x * 2, t = threadIdx.x;
  int h = t >> 7, c = t & 127;
  #pragma unroll
  for (int rr = 0; rr < 2; ++rr) {
    int i = i0 + rr;
    if (h == 0) {
      int row = (i & 3) * 128 + c;
      float s = ws[OFF_SUMS + row];
      sain[rr][c] = ws[OFF_OUT + row * CDIM + (i >> 2)] / s;
    } else {
      float s = ws[OFF_SUMS + 512 + i];
      dain[rr][c] = ws[OFF_OUT + NQ * CDIM + i * CDIM + c] / s;
    }
  }
  __syncthreads();
  {
    const float4* w4 = (const float4*)((h ? pda : psa) + c * CDIM);
    const float* in0 = h ? dain[0] : sain[0];
    const float* in1 = h ? dain[1] : sain[1];
    float a0 = 0, a1 = 0, b0 = 0, b1 = 0;
    #pragma unroll 8
    for (int j4 = 0; j4 < 32; ++j4) {
      float4 wv = w4[j4];
      float4 x0 = *(const float4*)&in0[j4 * 4];
      float4 x1 = *(const float4*)&in1[j4 * 4];
      a0 = fmaf(wv.x, x0.x, a0); a1 = fmaf(wv.y, x0.y, a1);
      a0 = fmaf(wv.z, x0.z, a0); a1 = fmaf(wv.w, x0.w, a1);
      b0 = fmaf(wv.x, x1.x, b0); b1 = fmaf(wv.y, x1.y, b1);
      b0 = fmaf(wv.z, x1.z, b0); b1 = fmaf(wv.w, x1.w, b1);
    }
    float bias = h ? bda[c] : bsa[c];
    cat[0][h * CDIM + c] = bias + a0 + a1;
    cat[1][h * CDIM + c] = bias + b0 + b1;
  }
  __syncthreads();
  {
    const float4* g4 = (const float4*)((h ? gda : gsa) + c * 2 * CDIM);
    float a0 = 0, a1 = 0, b0 = 0, b1 = 0;
    #pragma unroll 8
    for (int j4 = 0; j4 < 64; ++j4) {
      float4 gv = g4[j4];
      float4 c0 = *(const float4*)&cat[0][j4 * 4];
      float4 c1 = *(const float4*)&cat[1][j4 * 4];
      a0 = fmaf(gv.x, c0.x, a0); a1 = fmaf(gv.y, c0.y, a1);
      a0 = fmaf(gv.z, c0.z, a0); a1 = fmaf(gv.w, c0.w, a1);
      b0 = fmaf(gv.x, c1.x, b0); b1 = fmaf(gv.y, c1.y, b1);
      b0 = fmaf(gv.z, c1.z, b0); b1 = fmaf(gv.w, c1.w, b1);
    }
    gl[0][h][c] = 1.0f / (1.0f + __expf(-(a0 + a1)));
    gl[1][h][c] = 1.0f / (1.0f + __expf(-(b0 + b1)));
  }
  __syncthreads();
  {
    int i = i0 + h;
    out[c * NQ + i] = gl[h][0][c] * cat[h][c] + gl[h][1][c] * cat[h][CDIM + c];
  }
}

// ---------------------------------------------------------------- launch
extern "C" void kernel_launch(void* const* d_in, const int* in_sizes, int n_in,
                              void* d_out, int out_size, void* d_ws, size_t ws_size,
                              hipStream_t stream)
{
  (void)in_sizes; (void)n_in; (void)out_size; (void)ws_size;
  const float* erp       = (const float*)d_in[0];
  const float* ico       = (const float*)d_in[1];
  const float* coord     = (const float*)d_in[2];
  const float* wq_sa     = (const float*)d_in[3];
  const float* wkv_sa    = (const float*)d_in[4];
  const float* proj_sa_w = (const float*)d_in[5];
  const float* proj_sa_b = (const float*)d_in[6];
  const float* wq_da     = (const float*)d_in[7];
  const float* wkv_da    = (const float*)d_in[8];
  const float* wdelta    = (const float*)d_in[9];
  const float* proj_da_w = (const float*)d_in[10];
  const float* proj_da_b = (const float*)d_in[11];
  const float* gate_sa   = (const float*)d_in[12];
  const float* gate_da   = (const float*)d_in[13];
  float* out = (float*)d_out;
  float* ws  = (float*)d_ws;

  hipLaunchKernelGGL(prep_kernel, dim3(577), dim3(256), 0, stream,
                     erp, ico, wq_sa, wq_da, wkv_sa, wkv_da, wdelta, ws);
  hipLaunchKernelGGL(attn_kernel, dim3(1920), dim3(256), 0, stream,
                     coord, ws);
  hipLaunchKernelGGL(finalize_kernel, dim3(256), dim3(256), 0, stream,
                     proj_sa_w, proj_sa_b, proj_da_w, proj_da_b,
                     gate_sa, gate_da, out, ws);
}